// Round 3
// baseline (4413.615 us; speedup 1.0000x reference)
//
#include <hip/hip_runtime.h>

#define TT 2048
#define CC 1024

typedef __attribute__((ext_vector_type(8))) __bf16 bf16x8;
typedef __attribute__((ext_vector_type(4))) float f32x4;
typedef unsigned int u32;

__device__ __forceinline__ short f2bf(float f) {
  u32 u = __float_as_uint(f);
  u += 0x7fffu + ((u >> 16) & 1u);  // RTNE
  return (short)(u >> 16);
}

#if __has_builtin(__builtin_amdgcn_cvt_pk_bf16_f32)
__device__ __forceinline__ u32 pack2(float a, float b) {
  auto v = __builtin_amdgcn_cvt_pk_bf16_f32(a, b);
  return __builtin_bit_cast(u32, v);
}
#else
__device__ __forceinline__ u32 pack2(float a, float b) {
  u32 ua = __float_as_uint(a), ub = __float_as_uint(b);
  ua += 0x7fffu + ((ua >> 16) & 1u);
  ub += 0x7fffu + ((ub >> 16) & 1u);
  return (ua >> 16) | (ub & 0xffff0000u);
}
#endif

// ---------------- fp32 -> bf16 casts -----------------------------------------
__global__ void cvt_bf16(const float* __restrict__ in, short* __restrict__ out, int n4) {
  int i = blockIdx.x * blockDim.x + threadIdx.x;
  if (i >= n4) return;
  float4 f = reinterpret_cast<const float4*>(in)[i];
  short4 s;
  s.x = f2bf(f.x); s.y = f2bf(f.y); s.z = f2bf(f.z); s.w = f2bf(f.w);
  reinterpret_cast<short4*>(out)[i] = s;
}

// W_qkv cast: scale the Q block by 0.125 (exact, folds the attention scale).
__global__ void cvt_wqkv(const float* __restrict__ in, short* __restrict__ out, int n4) {
  int i = blockIdx.x * blockDim.x + threadIdx.x;
  if (i >= n4) return;
  float sc = (i * 4 < 1048576) ? 0.125f : 1.0f;
  float4 f = reinterpret_cast<const float4*>(in)[i];
  short4 s;
  s.x = f2bf(f.x * sc); s.y = f2bf(f.y * sc); s.z = f2bf(f.z * sc); s.w = f2bf(f.w * sc);
  reinterpret_cast<short4*>(out)[i] = s;
}

__device__ __forceinline__ void storev(float* p, float v) { *p = v; }
__device__ __forceinline__ void storev(short* p, float v) { *p = f2bf(v); }

#if __has_builtin(__builtin_amdgcn_global_load_lds)
#define HAVE_GLD_LDS 1
__device__ __forceinline__ void gld_lds16(const short* g, short* l) {
  __builtin_amdgcn_global_load_lds((const __attribute__((address_space(1))) u32*)g,
                                   (__attribute__((address_space(3))) u32*)l, 16, 0, 0);
}
#endif

// ---------------- C[M,N] = A[M,K] * B[N,K]^T  (bf16 in, fp32 acc) -------------
template <typename OutT>
__global__ __launch_bounds__(256) void gemm_bt(const short* __restrict__ A,
                                               const short* __restrict__ B,
                                               OutT* __restrict__ Cm,
                                               int M, int N, int K) {
  __shared__ __align__(16) short As[128 * 32];
  __shared__ __align__(16) short Bs[128 * 32];
  const int tid = threadIdx.x;
  const int wave = tid >> 6, lane = tid & 63;
  const int quad = lane >> 4, nl = lane & 15;
  const int m0 = blockIdx.x * 128, n0 = blockIdx.y * 128;
  const int wr = (wave >> 1) * 64, wc = (wave & 1) * 64;
  f32x4 acc[4][4] = {};
  for (int k0 = 0; k0 < K; k0 += 32) {
    __syncthreads();
#pragma unroll
    for (int i = 0; i < 2; ++i) {
      int idx = tid + i * 256;
      int row = idx >> 2, cg = idx & 3;
#if HAVE_GLD_LDS
      gld_lds16(&A[(size_t)(m0 + row) * K + k0 + cg * 8], &As[(i * 256 + wave * 64) * 8]);
      gld_lds16(&B[(size_t)(n0 + row) * K + k0 + cg * 8], &Bs[(i * 256 + wave * 64) * 8]);
#else
      *reinterpret_cast<uint4*>(&As[row * 32 + cg * 8]) =
          *reinterpret_cast<const uint4*>(&A[(size_t)(m0 + row) * K + k0 + cg * 8]);
      *reinterpret_cast<uint4*>(&Bs[row * 32 + cg * 8]) =
          *reinterpret_cast<const uint4*>(&B[(size_t)(n0 + row) * K + k0 + cg * 8]);
#endif
    }
    __syncthreads();
    bf16x8 af[4], bfr[4];
#pragma unroll
    for (int i = 0; i < 4; ++i)
      af[i] = *reinterpret_cast<const bf16x8*>(&As[(wr + i * 16 + nl) * 32 + quad * 8]);
#pragma unroll
    for (int i = 0; i < 4; ++i)
      bfr[i] = *reinterpret_cast<const bf16x8*>(&Bs[(wc + i * 16 + nl) * 32 + quad * 8]);
#pragma unroll
    for (int mi = 0; mi < 4; ++mi)
#pragma unroll
      for (int ni = 0; ni < 4; ++ni)
        acc[mi][ni] = __builtin_amdgcn_mfma_f32_16x16x32_bf16(af[mi], bfr[ni], acc[mi][ni], 0, 0, 0);
  }
#pragma unroll
  for (int mi = 0; mi < 4; ++mi)
#pragma unroll
    for (int ni = 0; ni < 4; ++ni) {
      int row = m0 + wr + mi * 16 + quad * 4;
      int col = n0 + wc + ni * 16 + nl;
#pragma unroll
      for (int r = 0; r < 4; ++r)
        storev(&Cm[(size_t)(row + r) * N + col], acc[mi][ni][r]);
    }
}

// ---------------- V transpose: qkv V-part -> Vt[bh][d][t] ---------------------
__global__ __launch_bounds__(256) void transpose_v(const short* __restrict__ qkv,
                                                   short* __restrict__ vt) {
  __shared__ short Ls[64 * 68];
  const int bh = blockIdx.y, tb = blockIdx.x;
  const int b = bh >> 4, h = bh & 15;
  const int tid = threadIdx.x;
  const short* src = qkv + (size_t)(b * TT + tb * 64) * (3 * CC) + 2 * CC + h * 64;
#pragma unroll
  for (int i = 0; i < 2; ++i) {
    int idx = tid + i * 256;
    int tl = idx >> 3, dc = idx & 7;
    uint4 d4 = *reinterpret_cast<const uint4*>(&src[(size_t)tl * (3 * CC) + dc * 8]);
    *reinterpret_cast<uint2*>(&Ls[tl * 68 + dc * 8]) = make_uint2(d4.x, d4.y);
    *reinterpret_cast<uint2*>(&Ls[tl * 68 + dc * 8 + 4]) = make_uint2(d4.z, d4.w);
  }
  __syncthreads();
  short* dst = vt + (size_t)(bh * 64) * TT + tb * 64;
#pragma unroll
  for (int i = 0; i < 2; ++i) {
    int idx = tid + i * 256;
    int dl = idx >> 3, tc = idx & 7;
    short tmp[8];
#pragma unroll
    for (int j = 0; j < 8; ++j) tmp[j] = Ls[(tc * 8 + j) * 68 + dl];
    *reinterpret_cast<uint4*>(&dst[(size_t)dl * TT + tc * 8]) = *reinterpret_cast<uint4*>(tmp);
  }
}

// ---------------- causal masked attention (no softmax) ------------------------
// 1 wave / block. grid (x=bh 64, y=strip 64): linear id % 8 == bh % 8 -> each
// XCD serves 8 heads (4 MB K+V = its L2). Strip qs = 63-y (big first) owns
// t in [qs*32, qs*32+31]. 32-col chunk loop: K register-double-buffered
// (prefetch next chunk during current), V loaded at chunk top, S round-trips
// a padded per-wave LDS buffer (stride 20 u32: 2-way max on writes = free).
__global__ __launch_bounds__(64, 4) void attn_kernel(const short* __restrict__ qkv,
                                                     const short* __restrict__ vt,
                                                     short* __restrict__ attnb) {
  const int bh = blockIdx.x;
  const int b = bh >> 4, h = bh & 15;
  const int qs = 63 - blockIdx.y;
  const int t0 = qs * 32;
  const int lane = threadIdx.x & 63;
  const int quad = lane >> 4, nl = lane & 15;

  const short* qbase = qkv + (size_t)(b * TT) * (3 * CC) + h * 64;
  const short* kbase = qbase + CC;
  const short* vbase = vt + (size_t)(bh * 64) * TT;

  __shared__ __align__(16) u32 Ss[2][2][16 * 20];  // [buf][m][t=16 rows x 20 u32]

  // Q B-frags (pre-scaled by 0.125): lane n=t0+m*16+nl, k=half*32+quad*8+j
  bf16x8 qf[2][2];
#pragma unroll
  for (int m = 0; m < 2; ++m)
#pragma unroll
    for (int half = 0; half < 2; ++half)
      qf[m][half] = *reinterpret_cast<const bf16x8*>(
          &qbase[(size_t)(t0 + m * 16 + nl) * (3 * CC) + half * 32 + quad * 8]);

  f32x4 o[2][4] = {};
  bf16x8 kA[2][2][2];  // [buf][st][half]: A-frag K[s0+st*16+nl][half*32+quad*8+j]

  // prefetch chunk 0
#pragma unroll
  for (int st = 0; st < 2; ++st)
#pragma unroll
    for (int half = 0; half < 2; ++half)
      kA[0][st][half] = *reinterpret_cast<const bf16x8*>(
          &kbase[(size_t)(st * 16 + nl) * (3 * CC) + half * 32 + quad * 8]);

  int cur = 0;
  for (int c = 0; c < qs; ++c) {  // full 32-chunks, no masking
    const int s0 = c * 32;
    // V for this chunk (consumed after QK+pack, ~150 cyc window)
    bf16x8 vB[4];
#pragma unroll
    for (int nb = 0; nb < 4; ++nb)
      vB[nb] = *reinterpret_cast<const bf16x8*>(
          &vbase[(size_t)(nb * 16 + nl) * TT + s0 + quad * 8]);
    // K prefetch for chunk c+1 (the last iteration prefetches the diagonal)
    const int s0n = s0 + 32;
#pragma unroll
    for (int st = 0; st < 2; ++st)
#pragma unroll
      for (int half = 0; half < 2; ++half)
        kA[cur ^ 1][st][half] = *reinterpret_cast<const bf16x8*>(
            &kbase[(size_t)(s0n + st * 16 + nl) * (3 * CC) + half * 32 + quad * 8]);
    // QK -> pack -> LDS
#pragma unroll
    for (int m = 0; m < 2; ++m) {
      u32* srow = &Ss[cur][m][nl * 20];
#pragma unroll
      for (int st = 0; st < 2; ++st) {
        f32x4 sacc = {};
        sacc = __builtin_amdgcn_mfma_f32_16x16x32_bf16(kA[cur][st][0], qf[m][0], sacc, 0, 0, 0);
        sacc = __builtin_amdgcn_mfma_f32_16x16x32_bf16(kA[cur][st][1], qf[m][1], sacc, 0, 0, 0);
#pragma unroll
        for (int p = 0; p < 2; ++p)
          srow[st * 8 + quad * 2 + p] = pack2(sacc[2 * p], sacc[2 * p + 1]);
      }
    }
    // LDS -> A-frag -> PV
#pragma unroll
    for (int m = 0; m < 2; ++m) {
      bf16x8 sf = *reinterpret_cast<const bf16x8*>(&Ss[cur][m][nl * 20 + quad * 4]);
#pragma unroll
      for (int nb = 0; nb < 4; ++nb)
        o[m][nb] = __builtin_amdgcn_mfma_f32_16x16x32_bf16(sf, vB[nb], o[m][nb], 0, 0, 0);
    }
    cur ^= 1;
  }

  // diagonal chunk (s0 = t0), kA[cur] already holds its K
  {
    bf16x8 vB[4];
#pragma unroll
    for (int nb = 0; nb < 4; ++nb)
      vB[nb] = *reinterpret_cast<const bf16x8*>(
          &vbase[(size_t)(nb * 16 + nl) * TT + t0 + quad * 8]);
    // m=0: st=0 triangular (s<=t: quad*4+r <= nl), st=1 all-masked -> zeros
    {
      u32* srow = &Ss[cur][0][nl * 20];
      f32x4 sacc = {};
      sacc = __builtin_amdgcn_mfma_f32_16x16x32_bf16(kA[cur][0][0], qf[0][0], sacc, 0, 0, 0);
      sacc = __builtin_amdgcn_mfma_f32_16x16x32_bf16(kA[cur][0][1], qf[0][1], sacc, 0, 0, 0);
#pragma unroll
      for (int r = 0; r < 4; ++r) sacc[r] = (quad * 4 + r <= nl) ? sacc[r] : 0.0f;
#pragma unroll
      for (int p = 0; p < 2; ++p) {
        srow[quad * 2 + p] = pack2(sacc[2 * p], sacc[2 * p + 1]);
        srow[8 + quad * 2 + p] = 0;
      }
    }
    // m=1: st=0 full, st=1 triangular
    {
      u32* srow = &Ss[cur][1][nl * 20];
      f32x4 s0acc = {}, s1acc = {};
      s0acc = __builtin_amdgcn_mfma_f32_16x16x32_bf16(kA[cur][0][0], qf[1][0], s0acc, 0, 0, 0);
      s0acc = __builtin_amdgcn_mfma_f32_16x16x32_bf16(kA[cur][0][1], qf[1][1], s0acc, 0, 0, 0);
      s1acc = __builtin_amdgcn_mfma_f32_16x16x32_bf16(kA[cur][1][0], qf[1][0], s1acc, 0, 0, 0);
      s1acc = __builtin_amdgcn_mfma_f32_16x16x32_bf16(kA[cur][1][1], qf[1][1], s1acc, 0, 0, 0);
#pragma unroll
      for (int r = 0; r < 4; ++r) s1acc[r] = (quad * 4 + r <= nl) ? s1acc[r] : 0.0f;
#pragma unroll
      for (int p = 0; p < 2; ++p) {
        srow[quad * 2 + p] = pack2(s0acc[2 * p], s0acc[2 * p + 1]);
        srow[8 + quad * 2 + p] = pack2(s1acc[2 * p], s1acc[2 * p + 1]);
      }
    }
#pragma unroll
    for (int m = 0; m < 2; ++m) {
      bf16x8 sf = *reinterpret_cast<const bf16x8*>(&Ss[cur][m][nl * 20 + quad * 4]);
#pragma unroll
      for (int nb = 0; nb < 4; ++nb)
        o[m][nb] = __builtin_amdgcn_mfma_f32_16x16x32_bf16(sf, vB[nb], o[m][nb], 0, 0, 0);
    }
  }

  // epilogue: O C-layout row=t(quad*4+r), col=d(nl) -> attnb[b][t][h*64+d]
#pragma unroll
  for (int m = 0; m < 2; ++m)
#pragma unroll
    for (int nb = 0; nb < 4; ++nb)
#pragma unroll
      for (int r = 0; r < 4; ++r) {
        int t = t0 + m * 16 + quad * 4 + r;
        attnb[(size_t)(b * TT + t) * CC + h * 64 + nb * 16 + nl] = f2bf(o[m][nb][r]);
      }
}

extern "C" void kernel_launch(void* const* d_in, const int* in_sizes, int n_in,
                              void* d_out, int out_size, void* d_ws, size_t ws_size,
                              hipStream_t stream) {
  const float* x = (const float*)d_in[0];      // [4,2048,1024]
  const float* wqkv = (const float*)d_in[1];   // [3072,1024]
  const float* wout = (const float*)d_in[2];   // [1024,1024]
  float* out = (float*)d_out;                  // [4,2048,1024] fp32

  char* ws = (char*)d_ws;
  short* xb    = (short*)(ws);                  // 16.78 MB
  short* wqkvb = (short*)(ws + 16777216);       //  6.29 MB
  short* woutb = (short*)(ws + 23068672);       //  2.10 MB
  short* qkvb  = (short*)(ws + 25165824);       // 50.33 MB
  short* attnb = (short*)(ws + 75497472);       // 16.78 MB  (total 92.27 MB)
  short* vt    = xb;  // xb dead after QKV GEMM

  cvt_bf16<<<8192, 256, 0, stream>>>(x, xb, 2097152);
  cvt_wqkv<<<3072, 256, 0, stream>>>(wqkv, wqkvb, 786432);
  cvt_bf16<<<1024, 256, 0, stream>>>(wout, woutb, 262144);

  gemm_bt<short><<<dim3(64, 24), 256, 0, stream>>>(xb, wqkvb, qkvb, 8192, 3072, 1024);

  transpose_v<<<dim3(32, 64), 256, 0, stream>>>(qkvb, vt);

  attn_kernel<<<dim3(64, 64), 64, 0, stream>>>(qkvb, vt, attnb);

  gemm_bt<float><<<dim3(64, 8), 256, 0, stream>>>(attnb, woutb, out, 8192, 1024, 1024);
}

// Round 4
// 323.642 us; speedup vs baseline: 13.6373x; 13.6373x over previous
//
#include <hip/hip_runtime.h>

#define TT 2048
#define CC 1024

typedef __attribute__((ext_vector_type(8))) __bf16 bf16x8;
typedef __attribute__((ext_vector_type(4))) float f32x4;
typedef unsigned int u32;

__device__ __forceinline__ short f2bf(float f) {
  u32 u = __float_as_uint(f);
  u += 0x7fffu + ((u >> 16) & 1u);  // RTNE
  return (short)(u >> 16);
}

#if __has_builtin(__builtin_amdgcn_cvt_pk_bf16_f32)
__device__ __forceinline__ u32 pack2(float a, float b) {
  auto v = __builtin_amdgcn_cvt_pk_bf16_f32(a, b);
  return __builtin_bit_cast(u32, v);
}
#else
__device__ __forceinline__ u32 pack2(float a, float b) {
  u32 ua = __float_as_uint(a), ub = __float_as_uint(b);
  ua += 0x7fffu + ((ua >> 16) & 1u);
  ub += 0x7fffu + ((ub >> 16) & 1u);
  return (ua >> 16) | (ub & 0xffff0000u);
}
#endif

// ---------------- fp32 -> bf16 casts -----------------------------------------
__global__ void cvt_bf16(const float* __restrict__ in, short* __restrict__ out, int n4) {
  int i = blockIdx.x * blockDim.x + threadIdx.x;
  if (i >= n4) return;
  float4 f = reinterpret_cast<const float4*>(in)[i];
  short4 s;
  s.x = f2bf(f.x); s.y = f2bf(f.y); s.z = f2bf(f.z); s.w = f2bf(f.w);
  reinterpret_cast<short4*>(out)[i] = s;
}

// W_qkv cast: scale the Q block by 0.125 (exact, folds the attention scale).
__global__ void cvt_wqkv(const float* __restrict__ in, short* __restrict__ out, int n4) {
  int i = blockIdx.x * blockDim.x + threadIdx.x;
  if (i >= n4) return;
  float sc = (i * 4 < 1048576) ? 0.125f : 1.0f;
  float4 f = reinterpret_cast<const float4*>(in)[i];
  short4 s;
  s.x = f2bf(f.x * sc); s.y = f2bf(f.y * sc); s.z = f2bf(f.z * sc); s.w = f2bf(f.w * sc);
  reinterpret_cast<short4*>(out)[i] = s;
}

__device__ __forceinline__ void storev(float* p, float v) { *p = v; }
__device__ __forceinline__ void storev(short* p, float v) { *p = f2bf(v); }

#if __has_builtin(__builtin_amdgcn_global_load_lds)
#define HAVE_GLD_LDS 1
__device__ __forceinline__ void gld_lds16(const short* g, short* l) {
  __builtin_amdgcn_global_load_lds((const __attribute__((address_space(1))) u32*)g,
                                   (__attribute__((address_space(3))) u32*)l, 16, 0, 0);
}
#endif

// ---------------- C[M,N] = A[M,K] * B[N,K]^T  (bf16 in, fp32 acc) -------------
template <typename OutT>
__global__ __launch_bounds__(256) void gemm_bt(const short* __restrict__ A,
                                               const short* __restrict__ B,
                                               OutT* __restrict__ Cm,
                                               int M, int N, int K) {
  __shared__ __align__(16) short As[128 * 32];
  __shared__ __align__(16) short Bs[128 * 32];
  const int tid = threadIdx.x;
  const int wave = tid >> 6, lane = tid & 63;
  const int quad = lane >> 4, nl = lane & 15;
  const int m0 = blockIdx.x * 128, n0 = blockIdx.y * 128;
  const int wr = (wave >> 1) * 64, wc = (wave & 1) * 64;
  f32x4 acc[4][4] = {};
  for (int k0 = 0; k0 < K; k0 += 32) {
    __syncthreads();
#pragma unroll
    for (int i = 0; i < 2; ++i) {
      int idx = tid + i * 256;
      int row = idx >> 2, cg = idx & 3;
#if HAVE_GLD_LDS
      gld_lds16(&A[(size_t)(m0 + row) * K + k0 + cg * 8], &As[(i * 256 + wave * 64) * 8]);
      gld_lds16(&B[(size_t)(n0 + row) * K + k0 + cg * 8], &Bs[(i * 256 + wave * 64) * 8]);
#else
      *reinterpret_cast<uint4*>(&As[row * 32 + cg * 8]) =
          *reinterpret_cast<const uint4*>(&A[(size_t)(m0 + row) * K + k0 + cg * 8]);
      *reinterpret_cast<uint4*>(&Bs[row * 32 + cg * 8]) =
          *reinterpret_cast<const uint4*>(&B[(size_t)(n0 + row) * K + k0 + cg * 8]);
#endif
    }
    __syncthreads();
    bf16x8 af[4], bfr[4];
#pragma unroll
    for (int i = 0; i < 4; ++i)
      af[i] = *reinterpret_cast<const bf16x8*>(&As[(wr + i * 16 + nl) * 32 + quad * 8]);
#pragma unroll
    for (int i = 0; i < 4; ++i)
      bfr[i] = *reinterpret_cast<const bf16x8*>(&Bs[(wc + i * 16 + nl) * 32 + quad * 8]);
#pragma unroll
    for (int mi = 0; mi < 4; ++mi)
#pragma unroll
      for (int ni = 0; ni < 4; ++ni)
        acc[mi][ni] = __builtin_amdgcn_mfma_f32_16x16x32_bf16(af[mi], bfr[ni], acc[mi][ni], 0, 0, 0);
  }
#pragma unroll
  for (int mi = 0; mi < 4; ++mi)
#pragma unroll
    for (int ni = 0; ni < 4; ++ni) {
      int row = m0 + wr + mi * 16 + quad * 4;
      int col = n0 + wc + ni * 16 + nl;
#pragma unroll
      for (int r = 0; r < 4; ++r)
        storev(&Cm[(size_t)(row + r) * N + col], acc[mi][ni][r]);
    }
}

// ---------------- V transpose: qkv V-part -> Vt[bh][d][t] ---------------------
__global__ __launch_bounds__(256) void transpose_v(const short* __restrict__ qkv,
                                                   short* __restrict__ vt) {
  __shared__ short Ls[64 * 68];
  const int bh = blockIdx.y, tb = blockIdx.x;
  const int b = bh >> 4, h = bh & 15;
  const int tid = threadIdx.x;
  const short* src = qkv + (size_t)(b * TT + tb * 64) * (3 * CC) + 2 * CC + h * 64;
#pragma unroll
  for (int i = 0; i < 2; ++i) {
    int idx = tid + i * 256;
    int tl = idx >> 3, dc = idx & 7;
    uint4 d4 = *reinterpret_cast<const uint4*>(&src[(size_t)tl * (3 * CC) + dc * 8]);
    *reinterpret_cast<uint2*>(&Ls[tl * 68 + dc * 8]) = make_uint2(d4.x, d4.y);
    *reinterpret_cast<uint2*>(&Ls[tl * 68 + dc * 8 + 4]) = make_uint2(d4.z, d4.w);
  }
  __syncthreads();
  short* dst = vt + (size_t)(bh * 64) * TT + tb * 64;
#pragma unroll
  for (int i = 0; i < 2; ++i) {
    int idx = tid + i * 256;
    int dl = idx >> 3, tc = idx & 7;
    short tmp[8];
#pragma unroll
    for (int j = 0; j < 8; ++j) tmp[j] = Ls[(tc * 8 + j) * 68 + dl];
    *reinterpret_cast<uint4*>(&dst[(size_t)dl * TT + tc * 8]) = *reinterpret_cast<uint4*>(tmp);
  }
}

// ---------------- attention chunk step ----------------------------------------
// ALL register arrays indexed with compile-time constants only (the round-3
// regression was `kA[cur]` with runtime cur -> scratch spill -> 800 MB traffic).
__device__ __forceinline__ f32x4 mfma16(bf16x8 a, bf16x8 b, f32x4 c) {
  return __builtin_amdgcn_mfma_f32_16x16x32_bf16(a, b, c, 0, 0, 0);
}

template <bool PRE>
__device__ __forceinline__ void chunk_step(const short* kbase, const short* vbase,
                                           u32* SsBase, const bf16x8 (&qf)[2][2],
                                           f32x4 (&o)[2][4], bf16x8 (&kUse)[2][2],
                                           bf16x8 (&kNext)[2][2], int s0, int quad, int nl) {
  bf16x8 vB[4];
#pragma unroll
  for (int nb = 0; nb < 4; ++nb)
    vB[nb] = *reinterpret_cast<const bf16x8*>(&vbase[(size_t)(nb * 16 + nl) * TT + s0 + quad * 8]);
  if (PRE) {
    const int s0n = s0 + 32;
#pragma unroll
    for (int st = 0; st < 2; ++st)
#pragma unroll
      for (int half = 0; half < 2; ++half)
        kNext[st][half] = *reinterpret_cast<const bf16x8*>(
            &kbase[(size_t)(s0n + st * 16 + nl) * (3 * CC) + half * 32 + quad * 8]);
  }
#pragma unroll
  for (int m = 0; m < 2; ++m) {
    u32* srow = &SsBase[m * 320 + nl * 20];
#pragma unroll
    for (int st = 0; st < 2; ++st) {
      f32x4 sacc = {};
      sacc = mfma16(kUse[st][0], qf[m][0], sacc);
      sacc = mfma16(kUse[st][1], qf[m][1], sacc);
#pragma unroll
      for (int p = 0; p < 2; ++p)
        srow[st * 8 + quad * 2 + p] = pack2(sacc[2 * p], sacc[2 * p + 1]);
    }
  }
#pragma unroll
  for (int m = 0; m < 2; ++m) {
    bf16x8 sf = *reinterpret_cast<const bf16x8*>(&SsBase[m * 320 + nl * 20 + quad * 4]);
#pragma unroll
    for (int nb = 0; nb < 4; ++nb)
      o[m][nb] = mfma16(sf, vB[nb], o[m][nb]);
  }
}

// ---------------- causal masked attention (no softmax) ------------------------
// 1 wave / block. grid (x=bh 64, y=strip 64): linear id % 8 == bh % 8 -> each
// XCD serves 8 heads (4 MB K+V fits its L2). Strip qs = 63-y owns t in
// [qs*32, qs*32+31]. Chunk loop unrolled x2 with two STATIC K buffer sets.
__global__ __launch_bounds__(64, 4) void attn_kernel(const short* __restrict__ qkv,
                                                     const short* __restrict__ vt,
                                                     short* __restrict__ attnb) {
  const int bh = blockIdx.x;
  const int b = bh >> 4, h = bh & 15;
  const int qs = 63 - blockIdx.y;
  const int t0 = qs * 32;
  const int lane = threadIdx.x & 63;
  const int quad = lane >> 4, nl = lane & 15;

  const short* qbase = qkv + (size_t)(b * TT) * (3 * CC) + h * 64;
  const short* kbase = qbase + CC;
  const short* vbase = vt + (size_t)(bh * 64) * TT;

  __shared__ __align__(16) u32 Ss[2 * 16 * 20];  // [m][t=16 rows x 20 u32]

  // Q B-frags (pre-scaled by 0.125): lane n=t0+m*16+nl, k=half*32+quad*8+j
  bf16x8 qf[2][2];
#pragma unroll
  for (int m = 0; m < 2; ++m)
#pragma unroll
    for (int half = 0; half < 2; ++half)
      qf[m][half] = *reinterpret_cast<const bf16x8*>(
          &qbase[(size_t)(t0 + m * 16 + nl) * (3 * CC) + half * 32 + quad * 8]);

  f32x4 o[2][4] = {};
  bf16x8 kA_A[2][2], kA_B[2][2];

  if (qs > 0) {
    // prefetch chunk 0 into kA_A
#pragma unroll
    for (int st = 0; st < 2; ++st)
#pragma unroll
      for (int half = 0; half < 2; ++half)
        kA_A[st][half] = *reinterpret_cast<const bf16x8*>(
            &kbase[(size_t)(st * 16 + nl) * (3 * CC) + half * 32 + quad * 8]);
    int c = 0;
    for (; c + 2 <= qs; c += 2) {
      chunk_step<true>(kbase, vbase, Ss, qf, o, kA_A, kA_B, c * 32, quad, nl);
      chunk_step<true>(kbase, vbase, Ss, qf, o, kA_B, kA_A, (c + 1) * 32, quad, nl);
    }
    if (c < qs)
      chunk_step<false>(kbase, vbase, Ss, qf, o, kA_A, kA_B, c * 32, quad, nl);
  }

  // diagonal chunk (s0 = t0): load its K fresh (one stall per block, negligible)
  {
    bf16x8 kD[2][2];
#pragma unroll
    for (int st = 0; st < 2; ++st)
#pragma unroll
      for (int half = 0; half < 2; ++half)
        kD[st][half] = *reinterpret_cast<const bf16x8*>(
            &kbase[(size_t)(t0 + st * 16 + nl) * (3 * CC) + half * 32 + quad * 8]);
    bf16x8 vB[4];
#pragma unroll
    for (int nb = 0; nb < 4; ++nb)
      vB[nb] = *reinterpret_cast<const bf16x8*>(
          &vbase[(size_t)(nb * 16 + nl) * TT + t0 + quad * 8]);
    // m=0: st=0 triangular (s<=t: quad*4+r <= nl), st=1 fully masked -> zeros
    {
      u32* srow = &Ss[0 * 320 + nl * 20];
      f32x4 sacc = {};
      sacc = mfma16(kD[0][0], qf[0][0], sacc);
      sacc = mfma16(kD[0][1], qf[0][1], sacc);
#pragma unroll
      for (int r = 0; r < 4; ++r) sacc[r] = (quad * 4 + r <= nl) ? sacc[r] : 0.0f;
#pragma unroll
      for (int p = 0; p < 2; ++p) {
        srow[quad * 2 + p] = pack2(sacc[2 * p], sacc[2 * p + 1]);
        srow[8 + quad * 2 + p] = 0;
      }
    }
    // m=1: st=0 full, st=1 triangular
    {
      u32* srow = &Ss[1 * 320 + nl * 20];
      f32x4 s0acc = {}, s1acc = {};
      s0acc = mfma16(kD[0][0], qf[1][0], s0acc);
      s0acc = mfma16(kD[0][1], qf[1][1], s0acc);
      s1acc = mfma16(kD[1][0], qf[1][0], s1acc);
      s1acc = mfma16(kD[1][1], qf[1][1], s1acc);
#pragma unroll
      for (int r = 0; r < 4; ++r) s1acc[r] = (quad * 4 + r <= nl) ? s1acc[r] : 0.0f;
#pragma unroll
      for (int p = 0; p < 2; ++p) {
        srow[quad * 2 + p] = pack2(s0acc[2 * p], s0acc[2 * p + 1]);
        srow[8 + quad * 2 + p] = pack2(s1acc[2 * p], s1acc[2 * p + 1]);
      }
    }
#pragma unroll
    for (int m = 0; m < 2; ++m) {
      bf16x8 sf = *reinterpret_cast<const bf16x8*>(&Ss[m * 320 + nl * 20 + quad * 4]);
#pragma unroll
      for (int nb = 0; nb < 4; ++nb)
        o[m][nb] = mfma16(sf, vB[nb], o[m][nb]);
    }
  }

  // epilogue: O C-layout row=t(quad*4+r), col=d(nl) -> attnb[b][t][h*64+d]
#pragma unroll
  for (int m = 0; m < 2; ++m)
#pragma unroll
    for (int nb = 0; nb < 4; ++nb)
#pragma unroll
      for (int r = 0; r < 4; ++r) {
        int t = t0 + m * 16 + quad * 4 + r;
        attnb[(size_t)(b * TT + t) * CC + h * 64 + nb * 16 + nl] = f2bf(o[m][nb][r]);
      }
}

extern "C" void kernel_launch(void* const* d_in, const int* in_sizes, int n_in,
                              void* d_out, int out_size, void* d_ws, size_t ws_size,
                              hipStream_t stream) {
  const float* x = (const float*)d_in[0];      // [4,2048,1024]
  const float* wqkv = (const float*)d_in[1];   // [3072,1024]
  const float* wout = (const float*)d_in[2];   // [1024,1024]
  float* out = (float*)d_out;                  // [4,2048,1024] fp32

  char* ws = (char*)d_ws;
  short* xb    = (short*)(ws);                  // 16.78 MB
  short* wqkvb = (short*)(ws + 16777216);       //  6.29 MB
  short* woutb = (short*)(ws + 23068672);       //  2.10 MB
  short* qkvb  = (short*)(ws + 25165824);       // 50.33 MB
  short* attnb = (short*)(ws + 75497472);       // 16.78 MB  (total 92.27 MB)
  short* vt    = xb;  // xb dead after QKV GEMM

  cvt_bf16<<<8192, 256, 0, stream>>>(x, xb, 2097152);
  cvt_wqkv<<<3072, 256, 0, stream>>>(wqkv, wqkvb, 786432);
  cvt_bf16<<<1024, 256, 0, stream>>>(wout, woutb, 262144);

  gemm_bt<short><<<dim3(64, 24), 256, 0, stream>>>(xb, wqkvb, qkvb, 8192, 3072, 1024);

  transpose_v<<<dim3(32, 64), 256, 0, stream>>>(qkvb, vt);

  attn_kernel<<<dim3(64, 64), 64, 0, stream>>>(qkvb, vt, attnb);

  gemm_bt<float><<<dim3(64, 8), 256, 0, stream>>>(attnb, woutb, out, 8192, 1024, 1024);
}

// Round 5
// 323.184 us; speedup vs baseline: 13.6567x; 1.0014x over previous
//
#include <hip/hip_runtime.h>

#define TT 2048
#define CC 1024

typedef __attribute__((ext_vector_type(8))) __bf16 bf16x8;
typedef __attribute__((ext_vector_type(4))) float f32x4;
typedef unsigned int u32;

__device__ __forceinline__ short f2bf(float f) {
  u32 u = __float_as_uint(f);
  u += 0x7fffu + ((u >> 16) & 1u);  // RTNE
  return (short)(u >> 16);
}

#if __has_builtin(__builtin_amdgcn_cvt_pk_bf16_f32)
__device__ __forceinline__ u32 pack2(float a, float b) {
  auto v = __builtin_amdgcn_cvt_pk_bf16_f32(a, b);
  return __builtin_bit_cast(u32, v);
}
#else
__device__ __forceinline__ u32 pack2(float a, float b) {
  u32 ua = __float_as_uint(a), ub = __float_as_uint(b);
  ua += 0x7fffu + ((ua >> 16) & 1u);
  ub += 0x7fffu + ((ub >> 16) & 1u);
  return (ua >> 16) | (ub & 0xffff0000u);
}
#endif

// ---------------- fp32 -> bf16 casts -----------------------------------------
__global__ void cvt_bf16(const float* __restrict__ in, short* __restrict__ out, int n4) {
  int i = blockIdx.x * blockDim.x + threadIdx.x;
  if (i >= n4) return;
  float4 f = reinterpret_cast<const float4*>(in)[i];
  short4 s;
  s.x = f2bf(f.x); s.y = f2bf(f.y); s.z = f2bf(f.z); s.w = f2bf(f.w);
  reinterpret_cast<short4*>(out)[i] = s;
}

// W_qkv cast: scale the Q block by 0.125 (exact, folds the attention scale).
__global__ void cvt_wqkv(const float* __restrict__ in, short* __restrict__ out, int n4) {
  int i = blockIdx.x * blockDim.x + threadIdx.x;
  if (i >= n4) return;
  float sc = (i * 4 < 1048576) ? 0.125f : 1.0f;
  float4 f = reinterpret_cast<const float4*>(in)[i];
  short4 s;
  s.x = f2bf(f.x * sc); s.y = f2bf(f.y * sc); s.z = f2bf(f.z * sc); s.w = f2bf(f.w * sc);
  reinterpret_cast<short4*>(out)[i] = s;
}

__device__ __forceinline__ void storev(float* p, float v) { *p = v; }
__device__ __forceinline__ void storev(short* p, float v) { *p = f2bf(v); }

#if __has_builtin(__builtin_amdgcn_global_load_lds)
#define HAVE_GLD_LDS 1
__device__ __forceinline__ void gld_lds16(const short* g, short* l) {
  __builtin_amdgcn_global_load_lds((const __attribute__((address_space(1))) u32*)g,
                                   (__attribute__((address_space(3))) u32*)l, 16, 0, 0);
}
#endif

// ---------------- C[M,N] = A[M,K] * B[N,K]^T  (bf16 in, fp32 acc) -------------
template <typename OutT>
__global__ __launch_bounds__(256) void gemm_bt(const short* __restrict__ A,
                                               const short* __restrict__ B,
                                               OutT* __restrict__ Cm,
                                               int M, int N, int K) {
  __shared__ __align__(16) short As[128 * 32];
  __shared__ __align__(16) short Bs[128 * 32];
  const int tid = threadIdx.x;
  const int wave = tid >> 6, lane = tid & 63;
  const int quad = lane >> 4, nl = lane & 15;
  const int m0 = blockIdx.x * 128, n0 = blockIdx.y * 128;
  const int wr = (wave >> 1) * 64, wc = (wave & 1) * 64;
  f32x4 acc[4][4] = {};
  for (int k0 = 0; k0 < K; k0 += 32) {
    __syncthreads();
#pragma unroll
    for (int i = 0; i < 2; ++i) {
      int idx = tid + i * 256;
      int row = idx >> 2, cg = idx & 3;
#if HAVE_GLD_LDS
      gld_lds16(&A[(size_t)(m0 + row) * K + k0 + cg * 8], &As[(i * 256 + wave * 64) * 8]);
      gld_lds16(&B[(size_t)(n0 + row) * K + k0 + cg * 8], &Bs[(i * 256 + wave * 64) * 8]);
#else
      *reinterpret_cast<uint4*>(&As[row * 32 + cg * 8]) =
          *reinterpret_cast<const uint4*>(&A[(size_t)(m0 + row) * K + k0 + cg * 8]);
      *reinterpret_cast<uint4*>(&Bs[row * 32 + cg * 8]) =
          *reinterpret_cast<const uint4*>(&B[(size_t)(n0 + row) * K + k0 + cg * 8]);
#endif
    }
    __syncthreads();
    bf16x8 af[4], bfr[4];
#pragma unroll
    for (int i = 0; i < 4; ++i)
      af[i] = *reinterpret_cast<const bf16x8*>(&As[(wr + i * 16 + nl) * 32 + quad * 8]);
#pragma unroll
    for (int i = 0; i < 4; ++i)
      bfr[i] = *reinterpret_cast<const bf16x8*>(&Bs[(wc + i * 16 + nl) * 32 + quad * 8]);
#pragma unroll
    for (int mi = 0; mi < 4; ++mi)
#pragma unroll
      for (int ni = 0; ni < 4; ++ni)
        acc[mi][ni] = __builtin_amdgcn_mfma_f32_16x16x32_bf16(af[mi], bfr[ni], acc[mi][ni], 0, 0, 0);
  }
#pragma unroll
  for (int mi = 0; mi < 4; ++mi)
#pragma unroll
    for (int ni = 0; ni < 4; ++ni) {
      int row = m0 + wr + mi * 16 + quad * 4;
      int col = n0 + wc + ni * 16 + nl;
#pragma unroll
      for (int r = 0; r < 4; ++r)
        storev(&Cm[(size_t)(row + r) * N + col], acc[mi][ni][r]);
    }
}

// ---------------- V transpose: qkv V-part -> Vt[bh][d][t] ---------------------
__global__ __launch_bounds__(256) void transpose_v(const short* __restrict__ qkv,
                                                   short* __restrict__ vt) {
  __shared__ short Ls[64 * 68];
  const int bh = blockIdx.y, tb = blockIdx.x;
  const int b = bh >> 4, h = bh & 15;
  const int tid = threadIdx.x;
  const short* src = qkv + (size_t)(b * TT + tb * 64) * (3 * CC) + 2 * CC + h * 64;
#pragma unroll
  for (int i = 0; i < 2; ++i) {
    int idx = tid + i * 256;
    int tl = idx >> 3, dc = idx & 7;
    uint4 d4 = *reinterpret_cast<const uint4*>(&src[(size_t)tl * (3 * CC) + dc * 8]);
    *reinterpret_cast<uint2*>(&Ls[tl * 68 + dc * 8]) = make_uint2(d4.x, d4.y);
    *reinterpret_cast<uint2*>(&Ls[tl * 68 + dc * 8 + 4]) = make_uint2(d4.z, d4.w);
  }
  __syncthreads();
  short* dst = vt + (size_t)(bh * 64) * TT + tb * 64;
#pragma unroll
  for (int i = 0; i < 2; ++i) {
    int idx = tid + i * 256;
    int dl = idx >> 3, tc = idx & 7;
    short tmp[8];
#pragma unroll
    for (int j = 0; j < 8; ++j) tmp[j] = Ls[(tc * 8 + j) * 68 + dl];
    *reinterpret_cast<uint4*>(&dst[(size_t)dl * TT + tc * 8]) = *reinterpret_cast<uint4*>(tmp);
  }
}

// ---------------- attention chunk step ----------------------------------------
// ALL register arrays indexed with compile-time constants only (round-3 lesson:
// runtime-indexed register arrays demote to scratch -> 800 MB HBM spill traffic).
__device__ __forceinline__ f32x4 mfma16(bf16x8 a, bf16x8 b, f32x4 c) {
  return __builtin_amdgcn_mfma_f32_16x16x32_bf16(a, b, c, 0, 0, 0);
}

template <bool PRE>
__device__ __forceinline__ void chunk_step(const short* kbase, const short* vbase,
                                           u32* ssw, const bf16x8 (&qf)[2][2],
                                           f32x4 (&o)[2][4], bf16x8 (&kUse)[2][2],
                                           bf16x8 (&kNext)[2][2], int s0, int quad, int nl) {
  bf16x8 vB[4];
#pragma unroll
  for (int nb = 0; nb < 4; ++nb)
    vB[nb] = *reinterpret_cast<const bf16x8*>(&vbase[(size_t)(nb * 16 + nl) * TT + s0 + quad * 8]);
  if (PRE) {
    const int s0n = s0 + 32;
#pragma unroll
    for (int st = 0; st < 2; ++st)
#pragma unroll
      for (int half = 0; half < 2; ++half)
        kNext[st][half] = *reinterpret_cast<const bf16x8*>(
            &kbase[(size_t)(s0n + st * 16 + nl) * (3 * CC) + half * 32 + quad * 8]);
  }
#pragma unroll
  for (int m = 0; m < 2; ++m) {
    u32* srow = &ssw[m * 320 + nl * 20];
#pragma unroll
    for (int st = 0; st < 2; ++st) {
      f32x4 sacc = {};
      sacc = mfma16(kUse[st][0], qf[m][0], sacc);
      sacc = mfma16(kUse[st][1], qf[m][1], sacc);
#pragma unroll
      for (int p = 0; p < 2; ++p)
        srow[st * 8 + quad * 2 + p] = pack2(sacc[2 * p], sacc[2 * p + 1]);
    }
  }
#pragma unroll
  for (int m = 0; m < 2; ++m) {
    bf16x8 sf = *reinterpret_cast<const bf16x8*>(&ssw[m * 320 + nl * 20 + quad * 4]);
#pragma unroll
    for (int nb = 0; nb < 4; ++nb)
      o[m][nb] = mfma16(sf, vB[nb], o[m][nb]);
  }
}

// Run full (unmasked) chunks [c0, c1) with a 2-set static K double-buffer.
__device__ __forceinline__ void run_chunks(const short* kbase, const short* vbase,
                                           u32* ssw, const bf16x8 (&qf)[2][2],
                                           f32x4 (&o)[2][4], int c0, int c1,
                                           int quad, int nl) {
  if (c0 >= c1) return;
  bf16x8 kA_A[2][2], kA_B[2][2];
#pragma unroll
  for (int st = 0; st < 2; ++st)
#pragma unroll
    for (int half = 0; half < 2; ++half)
      kA_A[st][half] = *reinterpret_cast<const bf16x8*>(
          &kbase[(size_t)(c0 * 32 + st * 16 + nl) * (3 * CC) + half * 32 + quad * 8]);
  int c = c0;
  for (; c + 2 <= c1; c += 2) {
    chunk_step<true>(kbase, vbase, ssw, qf, o, kA_A, kA_B, c * 32, quad, nl);
    chunk_step<true>(kbase, vbase, ssw, qf, o, kA_B, kA_A, (c + 1) * 32, quad, nl);
  }
  if (c < c1)
    chunk_step<false>(kbase, vbase, ssw, qf, o, kA_A, kA_B, c * 32, quad, nl);
}

// ---------------- causal masked attention (no softmax) ------------------------
// 2 waves / block (128 thr). grid (x=bh 64, y=strip 64): linear id % 8 == bh%8
// -> each XCD serves 8 heads (4 MB K+V fits its L2; round-4 FETCH=24.6 MB
// confirms). Strip qs = 63-y owns t in [qs*32, qs*32+31]. The chunk range is
// SPLIT across the 2 waves (wave0: [0,n0), wave1: [n0,qs)+diagonal) to double
// wave supply to 32/CU; partial O combined through an 8 KB LDS union guarded
// by two barriers (Ss regions are dead at barrier 1).
__global__ __launch_bounds__(128, 4) void attn_kernel(const short* __restrict__ qkv,
                                                      const short* __restrict__ vt,
                                                      short* __restrict__ attnb) {
  const int bh = blockIdx.x;
  const int b = bh >> 4, h = bh & 15;
  const int qs = 63 - blockIdx.y;
  const int t0 = qs * 32;
  const int tid = threadIdx.x;
  const int wave = tid >> 6, lane = tid & 63;
  const int quad = lane >> 4, nl = lane & 15;

  const short* qbase = qkv + (size_t)(b * TT) * (3 * CC) + h * 64;
  const short* kbase = qbase + CC;
  const short* vbase = vt + (size_t)(bh * 64) * TT;

  __shared__ __align__(16) u32 lds_raw[2048];  // 8 KB: Ss[2][640] during loops, comb after
  u32* ssw = &lds_raw[wave * 640];

  // Q B-frags (pre-scaled by 0.125): lane n=t0+m*16+nl, k=half*32+quad*8+j
  bf16x8 qf[2][2];
#pragma unroll
  for (int m = 0; m < 2; ++m)
#pragma unroll
    for (int half = 0; half < 2; ++half)
      qf[m][half] = *reinterpret_cast<const bf16x8*>(
          &qbase[(size_t)(t0 + m * 16 + nl) * (3 * CC) + half * 32 + quad * 8]);

  f32x4 o[2][4] = {};
  const int n0 = (qs + 1) >> 1;  // wave0: [0,n0) full chunks; wave1: [n0,qs) + diagonal

  if (wave == 0) {
    run_chunks(kbase, vbase, ssw, qf, o, 0, n0, quad, nl);
  } else {
    run_chunks(kbase, vbase, ssw, qf, o, n0, qs, quad, nl);
    // diagonal chunk (s0 = t0)
    bf16x8 kD[2][2];
#pragma unroll
    for (int st = 0; st < 2; ++st)
#pragma unroll
      for (int half = 0; half < 2; ++half)
        kD[st][half] = *reinterpret_cast<const bf16x8*>(
            &kbase[(size_t)(t0 + st * 16 + nl) * (3 * CC) + half * 32 + quad * 8]);
    bf16x8 vB[4];
#pragma unroll
    for (int nb = 0; nb < 4; ++nb)
      vB[nb] = *reinterpret_cast<const bf16x8*>(
          &vbase[(size_t)(nb * 16 + nl) * TT + t0 + quad * 8]);
    // m=0: st=0 triangular (s<=t: quad*4+r <= nl), st=1 fully masked -> zeros
    {
      u32* srow = &ssw[0 * 320 + nl * 20];
      f32x4 sacc = {};
      sacc = mfma16(kD[0][0], qf[0][0], sacc);
      sacc = mfma16(kD[0][1], qf[0][1], sacc);
#pragma unroll
      for (int r = 0; r < 4; ++r) sacc[r] = (quad * 4 + r <= nl) ? sacc[r] : 0.0f;
#pragma unroll
      for (int p = 0; p < 2; ++p) {
        srow[quad * 2 + p] = pack2(sacc[2 * p], sacc[2 * p + 1]);
        srow[8 + quad * 2 + p] = 0;
      }
    }
    // m=1: st=0 full, st=1 triangular
    {
      u32* srow = &ssw[1 * 320 + nl * 20];
      f32x4 s0acc = {}, s1acc = {};
      s0acc = mfma16(kD[0][0], qf[1][0], s0acc);
      s0acc = mfma16(kD[0][1], qf[1][1], s0acc);
      s1acc = mfma16(kD[1][0], qf[1][0], s1acc);
      s1acc = mfma16(kD[1][1], qf[1][1], s1acc);
#pragma unroll
      for (int r = 0; r < 4; ++r) s1acc[r] = (quad * 4 + r <= nl) ? s1acc[r] : 0.0f;
#pragma unroll
      for (int p = 0; p < 2; ++p) {
        srow[quad * 2 + p] = pack2(s0acc[2 * p], s0acc[2 * p + 1]);
        srow[8 + quad * 2 + p] = pack2(s1acc[2 * p], s1acc[2 * p + 1]);
      }
    }
#pragma unroll
    for (int m = 0; m < 2; ++m) {
      bf16x8 sf = *reinterpret_cast<const bf16x8*>(&ssw[m * 320 + nl * 20 + quad * 4]);
#pragma unroll
      for (int nb = 0; nb < 4; ++nb)
        o[m][nb] = mfma16(sf, vB[nb], o[m][nb]);
    }
  }

  // combine partial O: wave0 -> LDS (Ss regions dead after barrier 1)
  __syncthreads();
  float* comb = reinterpret_cast<float*>(lds_raw);
  if (wave == 0) {
#pragma unroll
    for (int m = 0; m < 2; ++m)
#pragma unroll
      for (int nb = 0; nb < 4; ++nb)
        *reinterpret_cast<f32x4*>(&comb[((m * 4 + nb) * 64 + lane) * 4]) = o[m][nb];
  }
  __syncthreads();
  if (wave == 1) {
#pragma unroll
    for (int m = 0; m < 2; ++m)
#pragma unroll
      for (int nb = 0; nb < 4; ++nb) {
        f32x4 p = *reinterpret_cast<const f32x4*>(&comb[((m * 4 + nb) * 64 + lane) * 4]);
        o[m][nb] += p;
      }
    // epilogue: O C-layout row=t(quad*4+r), col=d(nl) -> attnb[b][t][h*64+d]
#pragma unroll
    for (int m = 0; m < 2; ++m)
#pragma unroll
      for (int nb = 0; nb < 4; ++nb)
#pragma unroll
        for (int r = 0; r < 4; ++r) {
          int t = t0 + m * 16 + quad * 4 + r;
          attnb[(size_t)(b * TT + t) * CC + h * 64 + nb * 16 + nl] = f2bf(o[m][nb][r]);
        }
  }
}

extern "C" void kernel_launch(void* const* d_in, const int* in_sizes, int n_in,
                              void* d_out, int out_size, void* d_ws, size_t ws_size,
                              hipStream_t stream) {
  const float* x = (const float*)d_in[0];      // [4,2048,1024]
  const float* wqkv = (const float*)d_in[1];   // [3072,1024]
  const float* wout = (const float*)d_in[2];   // [1024,1024]
  float* out = (float*)d_out;                  // [4,2048,1024] fp32

  char* ws = (char*)d_ws;
  short* xb    = (short*)(ws);                  // 16.78 MB
  short* wqkvb = (short*)(ws + 16777216);       //  6.29 MB
  short* woutb = (short*)(ws + 23068672);       //  2.10 MB
  short* qkvb  = (short*)(ws + 25165824);       // 50.33 MB
  short* attnb = (short*)(ws + 75497472);       // 16.78 MB  (total 92.27 MB)
  short* vt    = xb;  // xb dead after QKV GEMM

  cvt_bf16<<<8192, 256, 0, stream>>>(x, xb, 2097152);
  cvt_wqkv<<<3072, 256, 0, stream>>>(wqkv, wqkvb, 786432);
  cvt_bf16<<<1024, 256, 0, stream>>>(wout, woutb, 262144);

  gemm_bt<short><<<dim3(64, 24), 256, 0, stream>>>(xb, wqkvb, qkvb, 8192, 3072, 1024);

  transpose_v<<<dim3(32, 64), 256, 0, stream>>>(qkvb, vt);

  attn_kernel<<<dim3(64, 64), 128, 0, stream>>>(qkvb, vt, attnb);

  gemm_bt<float><<<dim3(64, 8), 256, 0, stream>>>(attnb, woutb, out, 8192, 1024, 1024);
}

// Round 6
// 266.639 us; speedup vs baseline: 16.5528x; 1.2121x over previous
//
#include <hip/hip_runtime.h>

#define TT 2048
#define CC 1024

typedef __attribute__((ext_vector_type(8))) __bf16 bf16x8;
typedef __attribute__((ext_vector_type(4))) float f32x4;
typedef unsigned int u32;

__device__ __forceinline__ short f2bf(float f) {
  u32 u = __float_as_uint(f);
  u += 0x7fffu + ((u >> 16) & 1u);  // RTNE
  return (short)(u >> 16);
}

#if __has_builtin(__builtin_amdgcn_cvt_pk_bf16_f32)
__device__ __forceinline__ u32 pack2(float a, float b) {
  auto v = __builtin_amdgcn_cvt_pk_bf16_f32(a, b);
  return __builtin_bit_cast(u32, v);
}
#else
__device__ __forceinline__ u32 pack2(float a, float b) {
  u32 ua = __float_as_uint(a), ub = __float_as_uint(b);
  ua += 0x7fffu + ((ua >> 16) & 1u);
  ub += 0x7fffu + ((ub >> 16) & 1u);
  return (ua >> 16) | (ub & 0xffff0000u);
}
#endif

// ---------------- fp32 -> bf16 casts -----------------------------------------
__global__ void cvt_bf16(const float* __restrict__ in, short* __restrict__ out, int n4) {
  int i = blockIdx.x * blockDim.x + threadIdx.x;
  if (i >= n4) return;
  float4 f = reinterpret_cast<const float4*>(in)[i];
  short4 s;
  s.x = f2bf(f.x); s.y = f2bf(f.y); s.z = f2bf(f.z); s.w = f2bf(f.w);
  reinterpret_cast<short4*>(out)[i] = s;
}

// W_qkv cast: scale the Q block by 0.125 (exact, folds the attention scale).
__global__ void cvt_wqkv(const float* __restrict__ in, short* __restrict__ out, int n4) {
  int i = blockIdx.x * blockDim.x + threadIdx.x;
  if (i >= n4) return;
  float sc = (i * 4 < 1048576) ? 0.125f : 1.0f;
  float4 f = reinterpret_cast<const float4*>(in)[i];
  short4 s;
  s.x = f2bf(f.x * sc); s.y = f2bf(f.y * sc); s.z = f2bf(f.z * sc); s.w = f2bf(f.w * sc);
  reinterpret_cast<short4*>(out)[i] = s;
}

__device__ __forceinline__ void storev(float* p, float v) { *p = v; }
__device__ __forceinline__ void storev(short* p, float v) { *p = f2bf(v); }

#if __has_builtin(__builtin_amdgcn_global_load_lds)
#define HAVE_GLD_LDS 1
__device__ __forceinline__ void gld_lds16(const short* g, short* l) {
  __builtin_amdgcn_global_load_lds((const __attribute__((address_space(1))) u32*)g,
                                   (__attribute__((address_space(3))) u32*)l, 16, 0, 0);
}
#endif

// ---------------- C[M,N] = A[M,K] * B[N,K]^T  (bf16 in, fp32 acc) -------------
template <typename OutT>
__global__ __launch_bounds__(256) void gemm_bt(const short* __restrict__ A,
                                               const short* __restrict__ B,
                                               OutT* __restrict__ Cm,
                                               int M, int N, int K) {
  __shared__ __align__(16) short As[128 * 32];
  __shared__ __align__(16) short Bs[128 * 32];
  const int tid = threadIdx.x;
  const int wave = tid >> 6, lane = tid & 63;
  const int quad = lane >> 4, nl = lane & 15;
  const int m0 = blockIdx.x * 128, n0 = blockIdx.y * 128;
  const int wr = (wave >> 1) * 64, wc = (wave & 1) * 64;
  f32x4 acc[4][4] = {};
  for (int k0 = 0; k0 < K; k0 += 32) {
    __syncthreads();
#pragma unroll
    for (int i = 0; i < 2; ++i) {
      int idx = tid + i * 256;
      int row = idx >> 2, cg = idx & 3;
#if HAVE_GLD_LDS
      gld_lds16(&A[(size_t)(m0 + row) * K + k0 + cg * 8], &As[(i * 256 + wave * 64) * 8]);
      gld_lds16(&B[(size_t)(n0 + row) * K + k0 + cg * 8], &Bs[(i * 256 + wave * 64) * 8]);
#else
      *reinterpret_cast<uint4*>(&As[row * 32 + cg * 8]) =
          *reinterpret_cast<const uint4*>(&A[(size_t)(m0 + row) * K + k0 + cg * 8]);
      *reinterpret_cast<uint4*>(&Bs[row * 32 + cg * 8]) =
          *reinterpret_cast<const uint4*>(&B[(size_t)(n0 + row) * K + k0 + cg * 8]);
#endif
    }
    __syncthreads();
    bf16x8 af[4], bfr[4];
#pragma unroll
    for (int i = 0; i < 4; ++i)
      af[i] = *reinterpret_cast<const bf16x8*>(&As[(wr + i * 16 + nl) * 32 + quad * 8]);
#pragma unroll
    for (int i = 0; i < 4; ++i)
      bfr[i] = *reinterpret_cast<const bf16x8*>(&Bs[(wc + i * 16 + nl) * 32 + quad * 8]);
#pragma unroll
    for (int mi = 0; mi < 4; ++mi)
#pragma unroll
      for (int ni = 0; ni < 4; ++ni)
        acc[mi][ni] = __builtin_amdgcn_mfma_f32_16x16x32_bf16(af[mi], bfr[ni], acc[mi][ni], 0, 0, 0);
  }
#pragma unroll
  for (int mi = 0; mi < 4; ++mi)
#pragma unroll
    for (int ni = 0; ni < 4; ++ni) {
      int row = m0 + wr + mi * 16 + quad * 4;
      int col = n0 + wc + ni * 16 + nl;
#pragma unroll
      for (int r = 0; r < 4; ++r)
        storev(&Cm[(size_t)(row + r) * N + col], acc[mi][ni][r]);
    }
}

// ---------------- V transpose: qkv V-part -> Vt[bh][d][t] ---------------------
__global__ __launch_bounds__(256) void transpose_v(const short* __restrict__ qkv,
                                                   short* __restrict__ vt) {
  __shared__ short Ls[64 * 68];
  const int bh = blockIdx.y, tb = blockIdx.x;
  const int b = bh >> 4, h = bh & 15;
  const int tid = threadIdx.x;
  const short* src = qkv + (size_t)(b * TT + tb * 64) * (3 * CC) + 2 * CC + h * 64;
#pragma unroll
  for (int i = 0; i < 2; ++i) {
    int idx = tid + i * 256;
    int tl = idx >> 3, dc = idx & 7;
    uint4 d4 = *reinterpret_cast<const uint4*>(&src[(size_t)tl * (3 * CC) + dc * 8]);
    *reinterpret_cast<uint2*>(&Ls[tl * 68 + dc * 8]) = make_uint2(d4.x, d4.y);
    *reinterpret_cast<uint2*>(&Ls[tl * 68 + dc * 8 + 4]) = make_uint2(d4.z, d4.w);
  }
  __syncthreads();
  short* dst = vt + (size_t)(bh * 64) * TT + tb * 64;
#pragma unroll
  for (int i = 0; i < 2; ++i) {
    int idx = tid + i * 256;
    int dl = idx >> 3, tc = idx & 7;
    short tmp[8];
#pragma unroll
    for (int j = 0; j < 8; ++j) tmp[j] = Ls[(tc * 8 + j) * 68 + dl];
    *reinterpret_cast<uint4*>(&dst[(size_t)dl * TT + tc * 8]) = *reinterpret_cast<uint4*>(tmp);
  }
}

// ---------------- attention compute (one 32-col chunk, one wave) --------------
__device__ __forceinline__ f32x4 mfma16(bf16x8 a, bf16x8 b, f32x4 c) {
  return __builtin_amdgcn_mfma_f32_16x16x32_bf16(a, b, c, 0, 0, 0);
}

// Frag LDS layout (8 KB, staged per chunk by global_load_lds, frag-ordered):
//   K frag f=(st*2+half) at f*1024B: slot lane*16B = K[s0+st*16+(lane&15)][half*32+(lane>>4)*8 ..+8]
//   V frag nb at 4096+nb*1024B:      slot lane*16B = Vt[nb*16+(lane&15)][s0+(lane>>4)*8 ..+8]
// => every fragment read below is ds_read_b128 at (base + lane*16B): 2-way, free.
template <bool DIAG>
__device__ __forceinline__ void attn_compute(const short* Frag, u32* ssw,
                                             const bf16x8 (&qf)[2][2], f32x4 (&o)[2][4],
                                             int lane, int quad, int nl) {
  bf16x8 k00 = *reinterpret_cast<const bf16x8*>(&Frag[0 * 512 + lane * 8]);
  bf16x8 k01 = *reinterpret_cast<const bf16x8*>(&Frag[1 * 512 + lane * 8]);
  bf16x8 k10 = *reinterpret_cast<const bf16x8*>(&Frag[2 * 512 + lane * 8]);
  bf16x8 k11 = *reinterpret_cast<const bf16x8*>(&Frag[3 * 512 + lane * 8]);
  bf16x8 vB[4];
#pragma unroll
  for (int nb = 0; nb < 4; ++nb)
    vB[nb] = *reinterpret_cast<const bf16x8*>(&Frag[2048 + nb * 512 + lane * 8]);
  // S^T = K * Q^T: C-layout row = s_local (quad*4+r), col = t_local (nl).
  // m = 0 (rows t0w..t0w+15): DIAG -> st0 triangular (keep s<=t), st1 zero
  {
    u32* srow = &ssw[0 * 320 + nl * 20];
    f32x4 s0 = {};
    s0 = mfma16(k00, qf[0][0], s0);
    s0 = mfma16(k01, qf[0][1], s0);
    if (DIAG) {
#pragma unroll
      for (int r = 0; r < 4; ++r) s0[r] = (quad * 4 + r <= nl) ? s0[r] : 0.0f;
    }
#pragma unroll
    for (int p = 0; p < 2; ++p) srow[quad * 2 + p] = pack2(s0[2 * p], s0[2 * p + 1]);
    if (DIAG) {
#pragma unroll
      for (int p = 0; p < 2; ++p) srow[8 + quad * 2 + p] = 0;
    } else {
      f32x4 s1 = {};
      s1 = mfma16(k10, qf[0][0], s1);
      s1 = mfma16(k11, qf[0][1], s1);
#pragma unroll
      for (int p = 0; p < 2; ++p) srow[8 + quad * 2 + p] = pack2(s1[2 * p], s1[2 * p + 1]);
    }
  }
  // m = 1 (rows t0w+16..t0w+31): DIAG -> st0 full, st1 triangular
  {
    u32* srow = &ssw[1 * 320 + nl * 20];
    f32x4 s0 = {}, s1 = {};
    s0 = mfma16(k00, qf[1][0], s0);
    s0 = mfma16(k01, qf[1][1], s0);
    s1 = mfma16(k10, qf[1][0], s1);
    s1 = mfma16(k11, qf[1][1], s1);
    if (DIAG) {
#pragma unroll
      for (int r = 0; r < 4; ++r) s1[r] = (quad * 4 + r <= nl) ? s1[r] : 0.0f;
    }
#pragma unroll
    for (int p = 0; p < 2; ++p) {
      srow[quad * 2 + p] = pack2(s0[2 * p], s0[2 * p + 1]);
      srow[8 + quad * 2 + p] = pack2(s1[2 * p], s1[2 * p + 1]);
    }
  }
  // S (A-op) from Ss roundtrip; PV accumulate
#pragma unroll
  for (int m = 0; m < 2; ++m) {
    bf16x8 sf = *reinterpret_cast<const bf16x8*>(&ssw[m * 320 + nl * 20 + quad * 4]);
#pragma unroll
    for (int nb = 0; nb < 4; ++nb) o[m][nb] = mfma16(sf, vB[nb], o[m][nb]);
  }
}

// ---------------- causal masked attention (no softmax) ------------------------
// Block = 4 waves, q-tile 128 rows, one bh. grid (x=bh 64, y=tile 16) -> bh%8
// XCD-affine (round-4 FETCH=24.6MB confirms L2 residency). Wave w owns rows
// [T0+w*32, +32) end-to-end (no combine). Per chunk: 8 global_load_lds stage
// K+V in FRAGMENT ORDER (each 64B line fetched once per block, DMA path, no
// L1/VGPR 16-line-split loads), m97 2-barrier loop; waves past their causal
// diagonal skip compute but keep barriers.
__global__ __launch_bounds__(256, 4) void attn_kernel(const short* __restrict__ qkv,
                                                      const short* __restrict__ vt,
                                                      short* __restrict__ attnb) {
  const int bh = blockIdx.x;
  const int b = bh >> 4, h = bh & 15;
  const int ti = 15 - blockIdx.y;  // big tiles first
  const int T0 = ti * 128;
  const int tid = threadIdx.x;
  const int wave = tid >> 6, lane = tid & 63;
  const int quad = lane >> 4, nl = lane & 15;

  const short* qbase = qkv + (size_t)(b * TT) * (3 * CC) + h * 64;
  const short* kbase = qbase + CC;
  const short* vbase = vt + (size_t)(bh * 64) * TT;

  __shared__ __align__(16) short Frag[4096];  // 8 KB staged K/V frags
  __shared__ __align__(16) u32 Ss[4][640];    // per-wave S roundtrip (stride 20)
  u32* ssw = Ss[wave];

  const int tw0 = T0 + wave * 32;
  bf16x8 qf[2][2];  // Q B-frags (pre-scaled by 0.125)
#pragma unroll
  for (int m = 0; m < 2; ++m)
#pragma unroll
    for (int half = 0; half < 2; ++half)
      qf[m][half] = *reinterpret_cast<const bf16x8*>(
          &qbase[(size_t)(tw0 + m * 16 + nl) * (3 * CC) + half * 32 + quad * 8]);

  f32x4 o[2][4] = {};

  // DMA source (this wave stages K frag `wave` and V frag `wave`); lane decomp
  // (nl, quad) matches the frag-order slot layout documented above.
  const short* ksrc = kbase + (size_t)((wave >> 1) * 16 + nl) * (3 * CC) + (wave & 1) * 32 + quad * 8;
  const short* vsrc = vbase + (size_t)(wave * 16 + nl) * TT + quad * 8;
  short* kdst = &Frag[wave * 512];
  short* vdst = &Frag[2048 + wave * 512];

  const int nch = 4 * ti + 4;
  const int cd = 4 * ti + wave;  // this wave's diagonal chunk

  for (int c = 0; c < nch; ++c) {
    __syncthreads();
#if HAVE_GLD_LDS
    gld_lds16(ksrc + (size_t)c * 32 * (3 * CC), kdst);
    gld_lds16(vsrc + c * 32, vdst);
#else
    *reinterpret_cast<uint4*>(&kdst[lane * 8]) =
        *reinterpret_cast<const uint4*>(ksrc + (size_t)c * 32 * (3 * CC));
    *reinterpret_cast<uint4*>(&vdst[lane * 8]) =
        *reinterpret_cast<const uint4*>(vsrc + c * 32);
#endif
    __syncthreads();
    if (c < cd)
      attn_compute<false>(Frag, ssw, qf, o, lane, quad, nl);
    else if (c == cd)
      attn_compute<true>(Frag, ssw, qf, o, lane, quad, nl);
  }

  // epilogue: O C-layout row=t(quad*4+r), col=d(nl) -> attnb[b][t][h*64+d]
#pragma unroll
  for (int m = 0; m < 2; ++m)
#pragma unroll
    for (int nb = 0; nb < 4; ++nb)
#pragma unroll
      for (int r = 0; r < 4; ++r) {
        int t = tw0 + m * 16 + quad * 4 + r;
        attnb[(size_t)(b * TT + t) * CC + h * 64 + nb * 16 + nl] = f2bf(o[m][nb][r]);
      }
}

extern "C" void kernel_launch(void* const* d_in, const int* in_sizes, int n_in,
                              void* d_out, int out_size, void* d_ws, size_t ws_size,
                              hipStream_t stream) {
  const float* x = (const float*)d_in[0];      // [4,2048,1024]
  const float* wqkv = (const float*)d_in[1];   // [3072,1024]
  const float* wout = (const float*)d_in[2];   // [1024,1024]
  float* out = (float*)d_out;                  // [4,2048,1024] fp32

  char* ws = (char*)d_ws;
  short* xb    = (short*)(ws);                  // 16.78 MB
  short* wqkvb = (short*)(ws + 16777216);       //  6.29 MB
  short* woutb = (short*)(ws + 23068672);       //  2.10 MB
  short* qkvb  = (short*)(ws + 25165824);       // 50.33 MB
  short* attnb = (short*)(ws + 75497472);       // 16.78 MB  (total 92.27 MB)
  short* vt    = xb;  // xb dead after QKV GEMM

  cvt_bf16<<<8192, 256, 0, stream>>>(x, xb, 2097152);
  cvt_wqkv<<<3072, 256, 0, stream>>>(wqkv, wqkvb, 786432);
  cvt_bf16<<<1024, 256, 0, stream>>>(wout, woutb, 262144);

  gemm_bt<short><<<dim3(64, 24), 256, 0, stream>>>(xb, wqkvb, qkvb, 8192, 3072, 1024);

  transpose_v<<<dim3(32, 64), 256, 0, stream>>>(qkvb, vt);

  attn_kernel<<<dim3(64, 16), 256, 0, stream>>>(qkvb, vt, attnb);

  gemm_bt<float><<<dim3(64, 8), 256, 0, stream>>>(attnb, woutb, out, 8192, 1024, 1024);
}

// Round 7
// 250.230 us; speedup vs baseline: 17.6382x; 1.0656x over previous
//
#include <hip/hip_runtime.h>

#define TT 2048
#define CC 1024

typedef __attribute__((ext_vector_type(8))) __bf16 bf16x8;
typedef __attribute__((ext_vector_type(4))) float f32x4;
typedef unsigned int u32;

__device__ __forceinline__ short f2bf(float f) {
  u32 u = __float_as_uint(f);
  u += 0x7fffu + ((u >> 16) & 1u);  // RTNE
  return (short)(u >> 16);
}

#if __has_builtin(__builtin_amdgcn_cvt_pk_bf16_f32)
__device__ __forceinline__ u32 pack2(float a, float b) {
  auto v = __builtin_amdgcn_cvt_pk_bf16_f32(a, b);
  return __builtin_bit_cast(u32, v);
}
#else
__device__ __forceinline__ u32 pack2(float a, float b) {
  u32 ua = __float_as_uint(a), ub = __float_as_uint(b);
  ua += 0x7fffu + ((ua >> 16) & 1u);
  ub += 0x7fffu + ((ub >> 16) & 1u);
  return (ua >> 16) | (ub & 0xffff0000u);
}
#endif

// ---------------- fused fp32 -> bf16 cast (x | wqkv(Q scaled) | wout) ---------
// ws layout is contiguous: xb (2097152 f4) | wqkvb (786432 f4) | woutb (262144 f4).
// Region boundaries are block-aligned (8192 / 3072 / 1024 blocks) -> no divergence.
__global__ __launch_bounds__(256) void cvt_all(const float* __restrict__ x,
                                               const float* __restrict__ wqkv,
                                               const float* __restrict__ wout,
                                               short* __restrict__ dst) {
  int i = blockIdx.x * blockDim.x + threadIdx.x;  // float4 index, < 3145728
  const float* src;
  float sc = 1.0f;
  if (i < 2097152) {
    src = x + (size_t)i * 4;
  } else if (i < 2883584) {
    int j = i - 2097152;
    src = wqkv + (size_t)j * 4;
    if (j < 262144) sc = 0.125f;  // Q block: fold attention scale (exact pow2)
  } else {
    src = wout + (size_t)(i - 2883584) * 4;
  }
  float4 f = *reinterpret_cast<const float4*>(src);
  short4 s;
  s.x = f2bf(f.x * sc); s.y = f2bf(f.y * sc); s.z = f2bf(f.z * sc); s.w = f2bf(f.w * sc);
  reinterpret_cast<short4*>(dst)[i] = s;
}

__device__ __forceinline__ void storev(float* p, float v) { *p = v; }
__device__ __forceinline__ void storev(short* p, float v) { *p = f2bf(v); }

#if __has_builtin(__builtin_amdgcn_global_load_lds)
#define HAVE_GLD_LDS 1
__device__ __forceinline__ void gld_lds16(const short* g, short* l) {
  __builtin_amdgcn_global_load_lds((const __attribute__((address_space(1))) u32*)g,
                                   (__attribute__((address_space(3))) u32*)l, 16, 0, 0);
}
#endif

// ---------------- C[M,N] = A[M,K] * B[N,K]^T  (bf16 in, fp32 acc) -------------
template <typename OutT>
__global__ __launch_bounds__(256) void gemm_bt(const short* __restrict__ A,
                                               const short* __restrict__ B,
                                               OutT* __restrict__ Cm,
                                               int M, int N, int K) {
  __shared__ __align__(16) short As[128 * 32];
  __shared__ __align__(16) short Bs[128 * 32];
  const int tid = threadIdx.x;
  const int wave = tid >> 6, lane = tid & 63;
  const int quad = lane >> 4, nl = lane & 15;
  const int m0 = blockIdx.x * 128, n0 = blockIdx.y * 128;
  const int wr = (wave >> 1) * 64, wc = (wave & 1) * 64;
  f32x4 acc[4][4] = {};
  for (int k0 = 0; k0 < K; k0 += 32) {
    __syncthreads();
#pragma unroll
    for (int i = 0; i < 2; ++i) {
      int idx = tid + i * 256;
      int row = idx >> 2, cg = idx & 3;
#if HAVE_GLD_LDS
      gld_lds16(&A[(size_t)(m0 + row) * K + k0 + cg * 8], &As[(i * 256 + wave * 64) * 8]);
      gld_lds16(&B[(size_t)(n0 + row) * K + k0 + cg * 8], &Bs[(i * 256 + wave * 64) * 8]);
#else
      *reinterpret_cast<uint4*>(&As[row * 32 + cg * 8]) =
          *reinterpret_cast<const uint4*>(&A[(size_t)(m0 + row) * K + k0 + cg * 8]);
      *reinterpret_cast<uint4*>(&Bs[row * 32 + cg * 8]) =
          *reinterpret_cast<const uint4*>(&B[(size_t)(n0 + row) * K + k0 + cg * 8]);
#endif
    }
    __syncthreads();
    bf16x8 af[4], bfr[4];
#pragma unroll
    for (int i = 0; i < 4; ++i)
      af[i] = *reinterpret_cast<const bf16x8*>(&As[(wr + i * 16 + nl) * 32 + quad * 8]);
#pragma unroll
    for (int i = 0; i < 4; ++i)
      bfr[i] = *reinterpret_cast<const bf16x8*>(&Bs[(wc + i * 16 + nl) * 32 + quad * 8]);
#pragma unroll
    for (int mi = 0; mi < 4; ++mi)
#pragma unroll
      for (int ni = 0; ni < 4; ++ni)
        acc[mi][ni] = __builtin_amdgcn_mfma_f32_16x16x32_bf16(af[mi], bfr[ni], acc[mi][ni], 0, 0, 0);
  }
#pragma unroll
  for (int mi = 0; mi < 4; ++mi)
#pragma unroll
    for (int ni = 0; ni < 4; ++ni) {
      int row = m0 + wr + mi * 16 + quad * 4;
      int col = n0 + wc + ni * 16 + nl;
#pragma unroll
      for (int r = 0; r < 4; ++r)
        storev(&Cm[(size_t)(row + r) * N + col], acc[mi][ni][r]);
    }
}

// ---------------- V transpose: qkv V-part -> Vt[bh][d][t] ---------------------
__global__ __launch_bounds__(256) void transpose_v(const short* __restrict__ qkv,
                                                   short* __restrict__ vt) {
  __shared__ short Ls[64 * 68];
  const int bh = blockIdx.y, tb = blockIdx.x;
  const int b = bh >> 4, h = bh & 15;
  const int tid = threadIdx.x;
  const short* src = qkv + (size_t)(b * TT + tb * 64) * (3 * CC) + 2 * CC + h * 64;
#pragma unroll
  for (int i = 0; i < 2; ++i) {
    int idx = tid + i * 256;
    int tl = idx >> 3, dc = idx & 7;
    uint4 d4 = *reinterpret_cast<const uint4*>(&src[(size_t)tl * (3 * CC) + dc * 8]);
    *reinterpret_cast<uint2*>(&Ls[tl * 68 + dc * 8]) = make_uint2(d4.x, d4.y);
    *reinterpret_cast<uint2*>(&Ls[tl * 68 + dc * 8 + 4]) = make_uint2(d4.z, d4.w);
  }
  __syncthreads();
  short* dst = vt + (size_t)(bh * 64) * TT + tb * 64;
#pragma unroll
  for (int i = 0; i < 2; ++i) {
    int idx = tid + i * 256;
    int dl = idx >> 3, tc = idx & 7;
    short tmp[8];
#pragma unroll
    for (int j = 0; j < 8; ++j) tmp[j] = Ls[(tc * 8 + j) * 68 + dl];
    *reinterpret_cast<uint4*>(&dst[(size_t)dl * TT + tc * 8]) = *reinterpret_cast<uint4*>(tmp);
  }
}

// ---------------- attention compute (one 32-col half-chunk, one wave) ---------
__device__ __forceinline__ f32x4 mfma16(bf16x8 a, bf16x8 b, f32x4 c) {
  return __builtin_amdgcn_mfma_f32_16x16x32_bf16(a, b, c, 0, 0, 0);
}

// kf: 4 K frag slots (512 shorts each): f=st*2+half, content lane*8 =
//     K[s0+st*16+(lane&15)][half*32+(lane>>4)*8 ..+8]
// vf: 4 V frag slots: nb, content lane*8 = Vt[nb*16+(lane&15)][s0+(lane>>4)*8 ..+8]
// All reads: ds_read_b128 at base + lane*16B (2-way, free).
template <bool DIAG>
__device__ __forceinline__ void attn_compute(const short* kf, const short* vf, u32* ssw,
                                             const bf16x8 (&qf)[2][2], f32x4 (&o)[2][4],
                                             int lane, int quad, int nl) {
  bf16x8 k00 = *reinterpret_cast<const bf16x8*>(&kf[0 * 512 + lane * 8]);
  bf16x8 k01 = *reinterpret_cast<const bf16x8*>(&kf[1 * 512 + lane * 8]);
  bf16x8 k10 = *reinterpret_cast<const bf16x8*>(&kf[2 * 512 + lane * 8]);
  bf16x8 k11 = *reinterpret_cast<const bf16x8*>(&kf[3 * 512 + lane * 8]);
  bf16x8 vB[4];
#pragma unroll
  for (int nb = 0; nb < 4; ++nb)
    vB[nb] = *reinterpret_cast<const bf16x8*>(&vf[nb * 512 + lane * 8]);
  // S^T = K * Q^T: C-layout row = s_local (quad*4+r), col = t_local (nl).
  {
    u32* srow = &ssw[0 * 320 + nl * 20];
    f32x4 s0 = {};
    s0 = mfma16(k00, qf[0][0], s0);
    s0 = mfma16(k01, qf[0][1], s0);
    if (DIAG) {
#pragma unroll
      for (int r = 0; r < 4; ++r) s0[r] = (quad * 4 + r <= nl) ? s0[r] : 0.0f;
    }
#pragma unroll
    for (int p = 0; p < 2; ++p) srow[quad * 2 + p] = pack2(s0[2 * p], s0[2 * p + 1]);
    if (DIAG) {
#pragma unroll
      for (int p = 0; p < 2; ++p) srow[8 + quad * 2 + p] = 0;
    } else {
      f32x4 s1 = {};
      s1 = mfma16(k10, qf[0][0], s1);
      s1 = mfma16(k11, qf[0][1], s1);
#pragma unroll
      for (int p = 0; p < 2; ++p) srow[8 + quad * 2 + p] = pack2(s1[2 * p], s1[2 * p + 1]);
    }
  }
  {
    u32* srow = &ssw[1 * 320 + nl * 20];
    f32x4 s0 = {}, s1 = {};
    s0 = mfma16(k00, qf[1][0], s0);
    s0 = mfma16(k01, qf[1][1], s0);
    s1 = mfma16(k10, qf[1][0], s1);
    s1 = mfma16(k11, qf[1][1], s1);
    if (DIAG) {
#pragma unroll
      for (int r = 0; r < 4; ++r) s1[r] = (quad * 4 + r <= nl) ? s1[r] : 0.0f;
    }
#pragma unroll
    for (int p = 0; p < 2; ++p) {
      srow[quad * 2 + p] = pack2(s0[2 * p], s0[2 * p + 1]);
      srow[8 + quad * 2 + p] = pack2(s1[2 * p], s1[2 * p + 1]);
    }
  }
#pragma unroll
  for (int m = 0; m < 2; ++m) {
    bf16x8 sf = *reinterpret_cast<const bf16x8*>(&ssw[m * 320 + nl * 20 + quad * 4]);
#pragma unroll
    for (int nb = 0; nb < 4; ++nb) o[m][nb] = mfma16(sf, vB[nb], o[m][nb]);
  }
}

// ---------------- causal masked attention (no softmax) ------------------------
// Block = 4 waves, 128-row q-tile, one bh; grid (x=bh 64, y=tile 16) XCD-affine.
// 64-wide chunks, LDS DOUBLE-BUFFERED: stage chunk c+1 into Frag[(c+1)&1] right
// AFTER the barrier of iter c, compute chunk c from Frag[c&1]. The vmcnt(0) the
// compiler emits at the NEXT barrier is what drains stage(c+1) -> DMA has the
// full 32-MFMA compute phase of slack. 1 barrier / 64 cols (was 4).
__global__ __launch_bounds__(256, 3) void attn_kernel(const short* __restrict__ qkv,
                                                      const short* __restrict__ vt,
                                                      short* __restrict__ attnb) {
  const int bh = blockIdx.x;
  const int b = bh >> 4, h = bh & 15;
  const int ti = 15 - blockIdx.y;  // big tiles first
  const int T0 = ti * 128;
  const int tid = threadIdx.x;
  const int wave = tid >> 6, lane = tid & 63;
  const int quad = lane >> 4, nl = lane & 15;

  const short* qbase = qkv + (size_t)(b * TT) * (3 * CC) + h * 64;
  const short* kbase = qbase + CC;
  const short* vbase = vt + (size_t)(bh * 64) * TT;

  __shared__ __align__(16) short Frag[2][8192];  // 2 x 16 KB staged K/V frags
  __shared__ __align__(16) u32 Ss[4][640];       // per-wave S roundtrip (stride 20)
  u32* ssw = Ss[wave];

  const int tw0 = T0 + wave * 32;
  bf16x8 qf[2][2];  // Q B-frags (pre-scaled by 0.125)
#pragma unroll
  for (int m = 0; m < 2; ++m)
#pragma unroll
    for (int half = 0; half < 2; ++half)
      qf[m][half] = *reinterpret_cast<const bf16x8*>(
          &qbase[(size_t)(tw0 + m * 16 + nl) * (3 * CC) + half * 32 + quad * 8]);

  f32x4 o[2][4] = {};

  // staging: wave w stages K slots 2w,2w+1 (st=w, half 0/1) and V slots 2w,2w+1
  // ((sp,nb) = (w>>1, (w&1)*2 + {0,1})); 4 gld_lds per wave per 64-chunk.
  const short* ksrc = kbase + (size_t)(wave * 16 + nl) * (3 * CC) + quad * 8;
  const int sp_w = wave >> 1, nb0 = (wave & 1) * 2;
  const short* vsrc0 = vbase + (size_t)((nb0 + 0) * 16 + nl) * TT + sp_w * 32 + quad * 8;
  const short* vsrc1 = vbase + (size_t)((nb0 + 1) * 16 + nl) * TT + sp_w * 32 + quad * 8;

  auto stage = [&](short* fb, int c) {
    const size_t koff = (size_t)(c * 64) * (3 * CC);
#if HAVE_GLD_LDS
    gld_lds16(ksrc + koff, &fb[(2 * wave) * 512]);
    gld_lds16(ksrc + koff + 32, &fb[(2 * wave + 1) * 512]);
    gld_lds16(vsrc0 + c * 64, &fb[4096 + (2 * wave) * 512]);
    gld_lds16(vsrc1 + c * 64, &fb[4096 + (2 * wave + 1) * 512]);
#else
    *reinterpret_cast<uint4*>(&fb[(2 * wave) * 512 + lane * 8]) =
        *reinterpret_cast<const uint4*>(ksrc + koff);
    *reinterpret_cast<uint4*>(&fb[(2 * wave + 1) * 512 + lane * 8]) =
        *reinterpret_cast<const uint4*>(ksrc + koff + 32);
    *reinterpret_cast<uint4*>(&fb[4096 + (2 * wave) * 512 + lane * 8]) =
        *reinterpret_cast<const uint4*>(vsrc0 + c * 64);
    *reinterpret_cast<uint4*>(&fb[4096 + (2 * wave + 1) * 512 + lane * 8]) =
        *reinterpret_cast<const uint4*>(vsrc1 + c * 64);
#endif
  };

  const int nch = 2 * ti + 2;     // 64-col chunks
  const int cd = 4 * ti + wave;   // this wave's diagonal 32-chunk index

  stage(Frag[0], 0);
  for (int c = 0; c < nch; ++c) {
    __syncthreads();  // compiler vmcnt(0) here drains stage(c); buf[c&1] ready
    if (c + 1 < nch) stage(Frag[(c + 1) & 1], c + 1);  // overlaps compute below
    const short* fb = Frag[c & 1];
    const int c0 = 2 * c, c1 = 2 * c + 1;
    if (c0 < cd)
      attn_compute<false>(fb, fb + 4096, ssw, qf, o, lane, quad, nl);
    else if (c0 == cd)
      attn_compute<true>(fb, fb + 4096, ssw, qf, o, lane, quad, nl);
    if (c1 < cd)
      attn_compute<false>(fb + 2048, fb + 4096 + 2048, ssw, qf, o, lane, quad, nl);
    else if (c1 == cd)
      attn_compute<true>(fb + 2048, fb + 4096 + 2048, ssw, qf, o, lane, quad, nl);
  }

  // epilogue: O C-layout row=t(quad*4+r), col=d(nl) -> attnb[b][t][h*64+d]
#pragma unroll
  for (int m = 0; m < 2; ++m)
#pragma unroll
    for (int nb = 0; nb < 4; ++nb)
#pragma unroll
      for (int r = 0; r < 4; ++r) {
        int t = tw0 + m * 16 + quad * 4 + r;
        attnb[(size_t)(b * TT + t) * CC + h * 64 + nb * 16 + nl] = f2bf(o[m][nb][r]);
      }
}

extern "C" void kernel_launch(void* const* d_in, const int* in_sizes, int n_in,
                              void* d_out, int out_size, void* d_ws, size_t ws_size,
                              hipStream_t stream) {
  const float* x = (const float*)d_in[0];      // [4,2048,1024]
  const float* wqkv = (const float*)d_in[1];   // [3072,1024]
  const float* wout = (const float*)d_in[2];   // [1024,1024]
  float* out = (float*)d_out;                  // [4,2048,1024] fp32

  char* ws = (char*)d_ws;
  short* xb    = (short*)(ws);                  // 16.78 MB
  short* wqkvb = (short*)(ws + 16777216);       //  6.29 MB
  short* woutb = (short*)(ws + 23068672);       //  2.10 MB
  short* qkvb  = (short*)(ws + 25165824);       // 50.33 MB
  short* attnb = (short*)(ws + 75497472);       // 16.78 MB  (total 92.27 MB)
  short* vt    = xb;  // xb dead after QKV GEMM

  cvt_all<<<12288, 256, 0, stream>>>(x, wqkv, wout, xb);

  gemm_bt<short><<<dim3(64, 24), 256, 0, stream>>>(xb, wqkvb, qkvb, 8192, 3072, 1024);

  transpose_v<<<dim3(32, 64), 256, 0, stream>>>(qkvb, vt);

  attn_kernel<<<dim3(64, 16), 256, 0, stream>>>(qkvb, vt, attnb);

  gemm_bt<float><<<dim3(64, 8), 256, 0, stream>>>(attnb, woutb, out, 8192, 1024, 1024);
}